// Round 8
// baseline (90.645 us; speedup 1.0000x reference)
//
#include <hip/hip_runtime.h>
#include <math.h>

static constexpr int N   = 4096;  // IN_SIZE
static constexpr int H   = 5;     // HID
static constexpr int NO  = 2048;  // OUT_SIZE
static constexpr float FEPS = 1e-4f;
static constexpr int RPB   = 8;         // X rows per producer block
static constexpr int NBLK  = N / RPB;   // 512 producer blocks
static constexpr int NCONS = 256;       // consumer blocks
static constexpr int NR    = NO / NCONS; // 8 output rows per consumer

#if __has_builtin(__builtin_amdgcn_rcpf)
__device__ __forceinline__ float frcp(float x) { return __builtin_amdgcn_rcpf(x); }
#else
__device__ __forceinline__ float frcp(float x) { return 1.0f / x; }
#endif
#if __has_builtin(__builtin_amdgcn_rsqf)
__device__ __forceinline__ float frsq(float x) { return __builtin_amdgcn_rsqf(x); }
#else
__device__ __forceinline__ float frsq(float x) { return 1.0f / sqrtf(x); }
#endif

__device__ __forceinline__ float wave_reduce(float v) {
#pragma unroll
    for (int o = 32; o > 0; o >>= 1) v += __shfl_down(v, o, 64);
    return v;
}

// Lane-parallel Jacobi rotation, compile-time (p,q). Lane L (<25) holds
// a = A[L/5][L%5], u = U[L/5][L%5].
#define JROT(p, q)                                                            \
    {                                                                         \
        const float apq = __shfl(a, (p) * 5 + (q), 64);                       \
        const float app = __shfl(a, (p) * 5 + (p), 64);                       \
        const float aqq = __shfl(a, (q) * 5 + (q), 64);                       \
        const bool  skip =                                                    \
            (apq * apq) <= (1e-26f * (app * app + aqq * aqq) + 1e-38f);       \
        const float theta = (aqq - app) * frcp(2.0f * apq);                   \
        const float tden  = fabsf(theta) + sqrtf(theta * theta + 1.0f);       \
        const float ttv   = ((theta >= 0.0f) ? 1.0f : -1.0f) * frcp(tden);    \
        float cc = frsq(ttv * ttv + 1.0f);                                    \
        float ss = ttv * cc;                                                  \
        cc = skip ? 1.0f : cc;                                                \
        ss = skip ? 0.0f : ss;                                                \
        {                                                                     \
            const int  pr   = ((r == (p)) ? (q) : ((r == (q)) ? (p) : r));    \
            const float prt = __shfl(a, pr * 5 + c, 64);                      \
            a = (r == (p)) ? (cc * a - ss * prt)                              \
                           : ((r == (q)) ? (ss * prt + cc * a) : a);          \
        }                                                                     \
        {                                                                     \
            const int  pc   = ((c == (p)) ? (q) : ((c == (q)) ? (p) : c));    \
            const float prt = __shfl(a, r * 5 + pc, 64);                      \
            a = (c == (p)) ? (cc * a - ss * prt)                              \
                           : ((c == (q)) ? (ss * prt + cc * a) : a);          \
            const float urt = __shfl(u, r * 5 + pc, 64);                      \
            u = (c == (p)) ? (cc * u - ss * urt)                              \
                           : ((c == (q)) ? (ss * urt + cc * u) : u);          \
        }                                                                     \
    }

// Single dispatch, producer/consumer blocks.
//   blocks [0,512):  phase A — partial M over 8 X-rows -> Mp[b] (agent-scope
//                    stores), __threadfence (release), atomicAdd(sem), exit.
//   blocks [512,768): spin until sem==512 (acquire + s_sleep), then
//                    reduce Mp -> M, wave0 lane-parallel Jacobi -> ys,
//                    write 8 output rows. Fixed-order reduction -> bit-identical
//                    across consumers -> deterministic.
// Deadlock-free: >=2 blocks/CU (launch_bounds) -> >=512 slots; only 256
// consumers can spin, so >=256 slots always available to producers.
__global__ __launch_bounds__(256, 2) void k_fused(const float* __restrict__ X,
                                                  const float* __restrict__ W1,
                                                  const float* __restrict__ W2,
                                                  float* __restrict__ Z,
                                                  float* __restrict__ Mp,
                                                  unsigned int* __restrict__ sem) {
    const int t = threadIdx.x;

    if (blockIdx.x < NBLK) {
        // ================= producer =================
        const int b  = blockIdx.x;
        const int rb = b * RPB;
        const float4* W14 = reinterpret_cast<const float4*>(W1);

        float acc[RPB][H];
#pragma unroll
        for (int r = 0; r < RPB; ++r)
#pragma unroll
            for (int a = 0; a < H; ++a) acc[r][a] = 0.f;

#pragma unroll
        for (int c = 0; c < 4; ++c) {
            const int j4 = c * 256 + t;
            float wf[20];
            {
                const float4 f0 = W14[5 * j4 + 0];
                const float4 f1 = W14[5 * j4 + 1];
                const float4 f2 = W14[5 * j4 + 2];
                const float4 f3 = W14[5 * j4 + 3];
                const float4 f4 = W14[5 * j4 + 4];
                wf[0]=f0.x;  wf[1]=f0.y;  wf[2]=f0.z;  wf[3]=f0.w;
                wf[4]=f1.x;  wf[5]=f1.y;  wf[6]=f1.z;  wf[7]=f1.w;
                wf[8]=f2.x;  wf[9]=f2.y;  wf[10]=f2.z; wf[11]=f2.w;
                wf[12]=f3.x; wf[13]=f3.y; wf[14]=f3.z; wf[15]=f3.w;
                wf[16]=f4.x; wf[17]=f4.y; wf[18]=f4.z; wf[19]=f4.w;
            }
#pragma unroll
            for (int r = 0; r < RPB; ++r) {
                const float4 x = reinterpret_cast<const float4*>(
                                     X + (size_t)(rb + r) * N)[j4];
#pragma unroll
                for (int a = 0; a < H; ++a)
                    acc[r][a] += x.x * wf[a]      + x.y * wf[5 + a]
                               + x.z * wf[10 + a] + x.w * wf[15 + a];
            }
        }

        float pm[H][H];
#pragma unroll
        for (int a = 0; a < H; ++a)
#pragma unroll
            for (int bb = 0; bb < H; ++bb) pm[a][bb] = 0.f;
#pragma unroll
        for (int r = 0; r < RPB; ++r) {
            float w1r[H];
#pragma unroll
            for (int a = 0; a < H; ++a) w1r[a] = W1[(size_t)(rb + r) * H + a];
#pragma unroll
            for (int a = 0; a < H; ++a)
#pragma unroll
                for (int bb = 0; bb < H; ++bb) pm[a][bb] += w1r[a] * acc[r][bb];
        }

        __shared__ float sm[4][25];
        {
            const int lane = t & 63, wv = t >> 6;
#pragma unroll
            for (int a = 0; a < H; ++a)
#pragma unroll
                for (int bb = 0; bb < H; ++bb) {
                    const float v = wave_reduce(pm[a][bb]);
                    if (lane == 0) sm[wv][a * H + bb] = v;
                }
        }
        __syncthreads();
        if (t < 25) {
            const float v = sm[0][t] + sm[1][t] + sm[2][t] + sm[3][t];
            __hip_atomic_store(&Mp[b * 25 + t], v, __ATOMIC_RELAXED,
                               __HIP_MEMORY_SCOPE_AGENT);
        }
        __syncthreads();
        if (t == 0) {
            __threadfence();   // device-scope release of Mp stores
            __hip_atomic_fetch_add(sem, 1u, __ATOMIC_RELEASE,
                                   __HIP_MEMORY_SCOPE_AGENT);
        }
        return;
    }

    // ================= consumer =================
    if (t == 0) {
        while (__hip_atomic_load(sem, __ATOMIC_ACQUIRE,
                                 __HIP_MEMORY_SCOPE_AGENT) < (unsigned)NBLK)
            __builtin_amdgcn_s_sleep(2);
    }
    __syncthreads();
    __threadfence();   // device-scope acquire before reading Mp

    __shared__ float sred[10][26];
    __shared__ float Msum[25];
    __shared__ float ys[25];

    if (t < 250) {
        const int e = t % 25, g = t / 25;
        float s = 0.f;
        for (int p = g; p < NBLK; p += 10)
            s += __hip_atomic_load(&Mp[p * 25 + e], __ATOMIC_RELAXED,
                                   __HIP_MEMORY_SCOPE_AGENT);
        sred[g][e] = s;
    }
    __syncthreads();
    if (t < 25) {
        float s = 0.f;
#pragma unroll
        for (int g = 0; g < 10; ++g) s += sred[g][t];
        Msum[t] = s;
    }
    __syncthreads();

    if (t < 64) {
        const int r = t / 5, c = t % 5;
        const float m = (t < 25) ? Msum[t] : 0.f;
        float a = 0.f;
#pragma unroll
        for (int k = 0; k < H; ++k)
            a += __shfl(m, r * 5 + k, 64) * __shfl(m, c * 5 + k, 64);
        float u = (t < 25 && r == c) ? 1.0f : 0.0f;

        for (int sweep = 0; sweep < 6; ++sweep) {
            JROT(0, 1) JROT(0, 2) JROT(0, 3) JROT(0, 4) JROT(1, 2)
            JROT(1, 3) JROT(1, 4) JROT(2, 3) JROT(2, 4) JROT(3, 4)
        }

        const float ev = fmaxf(sqrtf(fmaxf(a, 0.0f)), FEPS);
        float yv = 0.f;
#pragma unroll
        for (int k = 0; k < H; ++k) {
            const float evk = __shfl(ev, 6 * k, 64);
            const float urk = __shfl(u, r * 5 + k, 64);
            const float uck = __shfl(u, c * 5 + k, 64);
            yv += evk * urk * uck;
        }
        if (t < 25) ys[t] = yv - ((r == c) ? FEPS : 0.f);
    }
    __syncthreads();

    const int i0 = (blockIdx.x - NBLK) * NR;
    float cmat[NR][H];
#pragma unroll
    for (int r = 0; r < NR; ++r) {
        float wcol[H];
#pragma unroll
        for (int k = 0; k < H; ++k) wcol[k] = W2[(size_t)k * NO + i0 + r];
#pragma unroll
        for (int m = 0; m < H; ++m) {
            float s = 0.f;
#pragma unroll
            for (int k = 0; k < H; ++k) s += wcol[k] * ys[k * H + m];
            cmat[r][m] = s;
        }
    }

#pragma unroll
    for (int hh = 0; hh < 2; ++hh) {
        const int jj = (hh * 256 + t) * 4;
        float4 w2j[H];
#pragma unroll
        for (int m = 0; m < H; ++m)
            w2j[m] = *reinterpret_cast<const float4*>(W2 + (size_t)m * NO + jj);
#pragma unroll
        for (int r = 0; r < NR; ++r) {
            const int i = i0 + r;
            float zx = 0.f, zy = 0.f, zz = 0.f, zw = 0.f;
#pragma unroll
            for (int m = 0; m < H; ++m) {
                const float cm = cmat[r][m];
                zx += cm * w2j[m].x;
                zy += cm * w2j[m].y;
                zz += cm * w2j[m].z;
                zw += cm * w2j[m].w;
            }
            if (i >= jj && i < jj + 4) {
                if      (i == jj + 0) zx += FEPS;
                else if (i == jj + 1) zy += FEPS;
                else if (i == jj + 2) zz += FEPS;
                else                  zw += FEPS;
            }
            *reinterpret_cast<float4*>(Z + (size_t)i * NO + jj) =
                make_float4(zx, zy, zz, zw);
        }
    }
}

extern "C" void kernel_launch(void* const* d_in, const int* in_sizes, int n_in,
                              void* d_out, int out_size, void* d_ws, size_t ws_size,
                              hipStream_t stream) {
    const float* X  = (const float*)d_in[0];
    const float* W1 = (const float*)d_in[1];
    const float* W2 = (const float*)d_in[2];
    float* out = (float*)d_out;
    float* ws  = (float*)d_ws;

    float* Mp = ws;                                   // NBLK*25 floats
    unsigned int* sem = (unsigned int*)(ws + NBLK * 25);

    (void)hipMemsetAsync(sem, 0, sizeof(unsigned int), stream);
    hipLaunchKernelGGL(k_fused, dim3(NBLK + NCONS), dim3(256), 0, stream,
                       X, W1, W2, out, Mp, sem);
}